// Round 1
// baseline (335.635 us; speedup 1.0000x reference)
//
#include <hip/hip_runtime.h>

#define S_LEN 2048
#define D_DIM 128
#define BM 64
#define BN 64
#define KROW (D_DIM + 8)   // 136 elems, 272 B row stride (16B aligned, 2-way bank)
#define VROW (BN + 8)      // 72 elems, 144 B row stride (16B aligned, 2-way bank)
#define PROW (BN + 8)      // 72

typedef __attribute__((ext_vector_type(8))) short short8;
typedef __attribute__((ext_vector_type(4))) float floatx4;

__device__ __forceinline__ unsigned short f2b(float f) {
    union { float f; unsigned u; } x; x.f = f;
    unsigned r = x.u + 0x7FFFu + ((x.u >> 16) & 1u);  // RNE
    return (unsigned short)(r >> 16);
}
__device__ __forceinline__ float b2f(unsigned short h) {
    union { unsigned u; float f; } x; x.u = ((unsigned)h) << 16;
    return x.f;
}

__global__ __launch_bounds__(256) void fa_fwd(const float* __restrict__ q,
                                              const float* __restrict__ k,
                                              const float* __restrict__ v,
                                              float* __restrict__ out) {
    __shared__ unsigned short Ks[BN][KROW];
    __shared__ unsigned short Vt[D_DIM][VROW];
    __shared__ unsigned short Ps[4][16][PROW];

    const int qt   = blockIdx.x;
    const int bh   = blockIdx.y;
    const int q0   = qt * BM;
    const int tid  = threadIdx.x;
    const int wave = tid >> 6;
    const int lane = tid & 63;
    const int ln   = lane & 15;
    const int quad = lane >> 4;
    const float scale = 0.08838834764831845f;  // 1/sqrt(128)

    // ---- Q fragments (A-layout: m = ln, k = quad*8+j), scale folded in ----
    const float* qrow = q + ((size_t)bh * S_LEN + q0 + wave * 16 + ln) * D_DIM;
    short8 qf[4];
    #pragma unroll
    for (int kc = 0; kc < 4; ++kc) {
        const float* p = qrow + kc * 32 + quad * 8;
        float4 x0 = *(const float4*)(p);
        float4 x1 = *(const float4*)(p + 4);
        short8 f;
        f[0] = (short)f2b(x0.x * scale); f[1] = (short)f2b(x0.y * scale);
        f[2] = (short)f2b(x0.z * scale); f[3] = (short)f2b(x0.w * scale);
        f[4] = (short)f2b(x1.x * scale); f[5] = (short)f2b(x1.y * scale);
        f[6] = (short)f2b(x1.z * scale); f[7] = (short)f2b(x1.w * scale);
        qf[kc] = f;
    }

    floatx4 o[8];
    #pragma unroll
    for (int db = 0; db < 8; ++db) o[db] = (floatx4){0.f, 0.f, 0.f, 0.f};
    float m_i[4] = {-1e30f, -1e30f, -1e30f, -1e30f};
    float l_i[4] = {0.f, 0.f, 0.f, 0.f};

    const size_t kvbase = (size_t)bh * S_LEN * D_DIM;

    for (int t = 0; t <= qt; ++t) {
        const int n0 = t * BN;
        const float* kb = k + kvbase + (size_t)n0 * D_DIM;
        const float* vb = v + kvbase + (size_t)n0 * D_DIM;

        // ---- stage K tile (row-major, bf16) ----
        #pragma unroll
        for (int i = 0; i < 8; ++i) {
            int e = i * 1024 + tid * 4;
            float4 x = *(const float4*)(kb + e);
            int r = e >> 7, c = e & 127;
            ushort4 h;
            h.x = f2b(x.x); h.y = f2b(x.y); h.z = f2b(x.z); h.w = f2b(x.w);
            *(ushort4*)&Ks[r][c] = h;
        }
        // ---- stage V transposed: Vt[d][kv] ----
        #pragma unroll
        for (int u = 0; u < 2; ++u) {
            int unit = u * 256 + tid;
            int r = (unit >> 5) * 4;   // kv row base, 0..60
            int c = (unit & 31) * 4;   // d col base,  0..124
            float4 x0 = *(const float4*)(vb + (r + 0) * D_DIM + c);
            float4 x1 = *(const float4*)(vb + (r + 1) * D_DIM + c);
            float4 x2 = *(const float4*)(vb + (r + 2) * D_DIM + c);
            float4 x3 = *(const float4*)(vb + (r + 3) * D_DIM + c);
            ushort4 h;
            h.x = f2b(x0.x); h.y = f2b(x1.x); h.z = f2b(x2.x); h.w = f2b(x3.x);
            *(ushort4*)&Vt[c + 0][r] = h;
            h.x = f2b(x0.y); h.y = f2b(x1.y); h.z = f2b(x2.y); h.w = f2b(x3.y);
            *(ushort4*)&Vt[c + 1][r] = h;
            h.x = f2b(x0.z); h.y = f2b(x1.z); h.z = f2b(x2.z); h.w = f2b(x3.z);
            *(ushort4*)&Vt[c + 2][r] = h;
            h.x = f2b(x0.w); h.y = f2b(x1.w); h.z = f2b(x2.w); h.w = f2b(x3.w);
            *(ushort4*)&Vt[c + 3][r] = h;
        }
        __syncthreads();

        // ---- S = (Q*scale) K^T, 16x64 per wave ----
        floatx4 sc[4];
        #pragma unroll
        for (int nb = 0; nb < 4; ++nb) {
            floatx4 acc = (floatx4){0.f, 0.f, 0.f, 0.f};
            #pragma unroll
            for (int kc = 0; kc < 4; ++kc) {
                short8 bfr = *(const short8*)&Ks[nb * 16 + ln][kc * 32 + quad * 8];
                acc = __builtin_amdgcn_mfma_f32_16x16x32_bf16(qf[kc], bfr, acc, 0, 0, 0);
            }
            sc[nb] = acc;
        }

        // ---- causal mask (diagonal tile only) ----
        if (t == qt) {
            int rowg = q0 + wave * 16 + quad * 4;
            #pragma unroll
            for (int nb = 0; nb < 4; ++nb) {
                int colg = n0 + nb * 16 + ln;
                #pragma unroll
                for (int r = 0; r < 4; ++r)
                    if (colg > rowg + r) sc[nb][r] = -1e30f;
            }
        }

        // ---- online softmax (rows live on 16 lanes of a quad) ----
        float mx[4];
        #pragma unroll
        for (int r = 0; r < 4; ++r)
            mx[r] = fmaxf(fmaxf(sc[0][r], sc[1][r]), fmaxf(sc[2][r], sc[3][r]));
        #pragma unroll
        for (int off = 1; off < 16; off <<= 1) {
            #pragma unroll
            for (int r = 0; r < 4; ++r)
                mx[r] = fmaxf(mx[r], __shfl_xor(mx[r], off));
        }
        float al[4], rs[4];
        #pragma unroll
        for (int r = 0; r < 4; ++r) {
            float mn = fmaxf(m_i[r], mx[r]);
            al[r] = __expf(m_i[r] - mn);
            m_i[r] = mn;
            rs[r] = 0.f;
        }
        #pragma unroll
        for (int nb = 0; nb < 4; ++nb) {
            #pragma unroll
            for (int r = 0; r < 4; ++r) {
                float p = __expf(sc[nb][r] - m_i[r]);
                unsigned short hb = f2b(p);
                Ps[wave][quad * 4 + r][nb * 16 + ln] = hb;
                rs[r] += b2f(hb);   // sum the rounded value: num/denom consistent
            }
        }
        #pragma unroll
        for (int off = 1; off < 16; off <<= 1) {
            #pragma unroll
            for (int r = 0; r < 4; ++r)
                rs[r] += __shfl_xor(rs[r], off);
        }
        #pragma unroll
        for (int r = 0; r < 4; ++r)
            l_i[r] = l_i[r] * al[r] + rs[r];
        #pragma unroll
        for (int db = 0; db < 8; ++db) {
            #pragma unroll
            for (int r = 0; r < 4; ++r) o[db][r] *= al[r];
        }

        // ---- P: C-layout -> A-layout via per-wave LDS tile ----
        short8 pf[2];
        #pragma unroll
        for (int kc = 0; kc < 2; ++kc)
            pf[kc] = *(const short8*)&Ps[wave][ln][kc * 32 + quad * 8];

        // ---- O += P V ----
        #pragma unroll
        for (int db = 0; db < 8; ++db) {
            floatx4 acc = o[db];
            #pragma unroll
            for (int kc = 0; kc < 2; ++kc) {
                short8 vf = *(const short8*)&Vt[db * 16 + ln][kc * 32 + quad * 8];
                acc = __builtin_amdgcn_mfma_f32_16x16x32_bf16(pf[kc], vf, acc, 0, 0, 0);
            }
            o[db] = acc;
        }
        __syncthreads();
    }

    // ---- epilogue: O / l ----
    #pragma unroll
    for (int r = 0; r < 4; ++r) {
        float inv = 1.f / l_i[r];
        size_t row = (size_t)bh * S_LEN + q0 + wave * 16 + quad * 4 + r;
        #pragma unroll
        for (int db = 0; db < 8; ++db)
            out[row * D_DIM + db * 16 + ln] = o[db][r] * inv;
    }
}

extern "C" void kernel_launch(void* const* d_in, const int* in_sizes, int n_in,
                              void* d_out, int out_size, void* d_ws, size_t ws_size,
                              hipStream_t stream) {
    const float* q = (const float*)d_in[0];
    const float* k = (const float*)d_in[1];
    const float* v = (const float*)d_in[2];
    float* out = (float*)d_out;
    int bh = in_sizes[0] / (S_LEN * D_DIM);   // B*H = 32
    dim3 grid(S_LEN / BM, bh);
    fa_fwd<<<grid, 256, 0, stream>>>(q, k, v, out);
}

// Round 2
// 261.835 us; speedup vs baseline: 1.2819x; 1.2819x over previous
//
#include <hip/hip_runtime.h>

#define S_LEN 2048
#define D_DIM 128
#define BM 128
#define BN 64

typedef __attribute__((ext_vector_type(8))) short short8;
typedef __attribute__((ext_vector_type(4))) float floatx4;
typedef unsigned short u16;

__device__ __forceinline__ u16 f2b(float f) {
    union { float f; unsigned u; } x; x.f = f;
    unsigned r = x.u + 0x7FFFu + ((x.u >> 16) & 1u);  // RNE
    return (u16)(r >> 16);
}
__device__ __forceinline__ float b2f(u16 h) {
    union { unsigned u; float f; } x; x.u = ((unsigned)h) << 16;
    return x.f;
}
__device__ __forceinline__ void gld_lds16(const void* g, void* l) {
    __builtin_amdgcn_global_load_lds(
        (const __attribute__((address_space(1))) unsigned int*)g,
        (__attribute__((address_space(3))) unsigned int*)l, 16, 0, 0);
}
__device__ __forceinline__ floatx4 mfma16(short8 a, short8 b, floatx4 c) {
    return __builtin_amdgcn_mfma_f32_16x16x32_bf16(a, b, c, 0, 0, 0);
}

// ---------------- pre-pass: K fp32 -> bf16 row-major ----------------
__global__ __launch_bounds__(256) void conv_k(const float* __restrict__ k,
                                              u16* __restrict__ kw) {
    int idx = (blockIdx.x * 256 + threadIdx.x) * 4;
    float4 x = *(const float4*)(k + idx);
    ushort4 h;
    h.x = f2b(x.x); h.y = f2b(x.y); h.z = f2b(x.z); h.w = f2b(x.w);
    *(ushort4*)(kw + idx) = h;
}

// ---------------- pre-pass: V fp32 [bh][s][d] -> bf16 [bh][d][s] ----------------
__global__ __launch_bounds__(256) void trans_v(const float* __restrict__ v,
                                               u16* __restrict__ vt) {
    __shared__ u16 T[D_DIM][72];   // 72-elem stride: rows 16B-aligned
    const int s0 = blockIdx.x * 64;
    const int bh = blockIdx.y;
    const float* vb = v + ((size_t)bh * S_LEN + s0) * D_DIM;
    #pragma unroll
    for (int i = 0; i < 8; ++i) {
        int e = (i * 256 + threadIdx.x) * 4;   // 64 x 128 tile
        int s = e >> 7, d = e & 127;
        float4 x = *(const float4*)(vb + e);
        T[d + 0][s] = f2b(x.x); T[d + 1][s] = f2b(x.y);
        T[d + 2][s] = f2b(x.z); T[d + 3][s] = f2b(x.w);
    }
    __syncthreads();
    u16* ob = vt + (size_t)bh * D_DIM * S_LEN + s0;
    #pragma unroll
    for (int i = 0; i < 4; ++i) {
        int g = i * 256 + threadIdx.x;  // 1024 granules of 16B
        int d = g >> 3, p = g & 7;
        uint4 val = *(const uint4*)&T[d][p * 8];
        *(uint4*)(ob + (size_t)d * S_LEN + p * 8) = val;
    }
}

// ---------------- main flash-attention kernel ----------------
__global__ __launch_bounds__(256, 2) void fa_main(const float* __restrict__ q,
                                                  const u16* __restrict__ kw,
                                                  const u16* __restrict__ vtw,
                                                  float* __restrict__ out) {
    __shared__ u16 Ks[BN * D_DIM];   // [64][128], XOR-swizzled granules
    __shared__ u16 Vt[D_DIM * BN];   // [128][64], XOR-swizzled granules
    __shared__ u16 Ps[4][32][72];    // per-wave P tile, padded

    const int qt   = blockIdx.x;
    const int bh   = blockIdx.y;
    const int q0   = qt * BM;
    const int tid  = threadIdx.x;
    const int w    = tid >> 6;
    const int lane = tid & 63;
    const int ln   = lane & 15;
    const int quad = lane >> 4;
    // scale * log2(e): softmax in exp2 domain
    constexpr float qs = 0.08838834764831845f * 1.44269504088896340f;

    const int rowb0 = q0 + w * 16;   // mtile0 global row base; mtile1 = +64

    // ---- Q fragments (A-layout), scale folded ----
    short8 qf[2][4];
    #pragma unroll
    for (int m = 0; m < 2; ++m) {
        const float* qrow = q + ((size_t)bh * S_LEN + rowb0 + m * 64 + ln) * D_DIM;
        #pragma unroll
        for (int kc = 0; kc < 4; ++kc) {
            const float* p = qrow + kc * 32 + quad * 8;
            float4 x0 = *(const float4*)(p);
            float4 x1 = *(const float4*)(p + 4);
            short8 f;
            f[0] = (short)f2b(x0.x * qs); f[1] = (short)f2b(x0.y * qs);
            f[2] = (short)f2b(x0.z * qs); f[3] = (short)f2b(x0.w * qs);
            f[4] = (short)f2b(x1.x * qs); f[5] = (short)f2b(x1.y * qs);
            f[6] = (short)f2b(x1.z * qs); f[7] = (short)f2b(x1.w * qs);
            qf[m][kc] = f;
        }
    }

    floatx4 o[2][8];
    #pragma unroll
    for (int m = 0; m < 2; ++m)
        #pragma unroll
        for (int db = 0; db < 8; ++db) o[m][db] = (floatx4){0.f, 0.f, 0.f, 0.f};
    float m_i[2][4], l_i[2][4];
    #pragma unroll
    for (int m = 0; m < 2; ++m)
        #pragma unroll
        for (int r = 0; r < 4; ++r) { m_i[m][r] = -1e30f; l_i[m][r] = 0.f; }

    const u16* kb_bh = kw + (size_t)bh * S_LEN * D_DIM;
    const u16* vb_bh = vtw + (size_t)bh * D_DIM * S_LEN;

    const int NT = 2 * qt + 2;
    for (int t = 0; t < NT; ++t) {
        const int n0 = t * BN;
        // ---- async stage K tile: 4 instrs/wave, 4 rows each ----
        {
            const u16* kb = kb_bh + (size_t)n0 * D_DIM;
            #pragma unroll
            for (int i = 0; i < 4; ++i) {
                int R0 = w * 16 + i * 4;
                int r = R0 + (lane >> 4);
                int p = lane & 15;
                gld_lds16(kb + r * D_DIM + (((p ^ (r & 7))) << 3), &Ks[R0 * D_DIM]);
            }
            // ---- async stage V tile (pre-transposed): 4 instrs/wave, 8 rows each ----
            #pragma unroll
            for (int i = 0; i < 4; ++i) {
                int D0 = (w * 4 + i) * 8;
                int d = D0 + (lane >> 3);
                int p = lane & 7;
                gld_lds16(vb_bh + (size_t)d * S_LEN + n0 + ((p ^ (d & 7)) << 3),
                          &Vt[D0 * BN]);
            }
        }
        __syncthreads();

        const bool skip0 = (n0 > rowb0 + 15);  // mtile0 fully masked (wave-uniform)

        // ---- S = Q K^T for both m-tiles, K frags shared ----
        floatx4 sc[2][4];
        #pragma unroll
        for (int nb = 0; nb < 4; ++nb) {
            short8 kf[4];
            #pragma unroll
            for (int kc = 0; kc < 4; ++kc) {
                int r = nb * 16 + ln;
                kf[kc] = *(const short8*)&Ks[r * D_DIM + (((kc * 4 + quad) ^ (r & 7)) << 3)];
            }
            floatx4 a0 = (floatx4){0.f, 0.f, 0.f, 0.f};
            floatx4 a1 = (floatx4){0.f, 0.f, 0.f, 0.f};
            #pragma unroll
            for (int kc = 0; kc < 4; ++kc) {
                if (!skip0) a0 = mfma16(qf[0][kc], kf[kc], a0);
                a1 = mfma16(qf[1][kc], kf[kc], a1);
            }
            sc[0][nb] = a0; sc[1][nb] = a1;
        }

        // ---- per-m-tile: mask, online softmax, P -> LDS ----
        #pragma unroll
        for (int m = 0; m < 2; ++m) {
            if (m == 0 && skip0) continue;
            const int rowb = rowb0 + m * 64;
            if (n0 + 63 > rowb) {   // diagonal tile: elementwise causal mask
                #pragma unroll
                for (int nb = 0; nb < 4; ++nb) {
                    int colg = n0 + nb * 16 + ln;
                    #pragma unroll
                    for (int r = 0; r < 4; ++r)
                        if (colg > rowb + quad * 4 + r) sc[m][nb][r] = -1e30f;
                }
            }
            float mx[4];
            #pragma unroll
            for (int r = 0; r < 4; ++r)
                mx[r] = fmaxf(fmaxf(sc[m][0][r], sc[m][1][r]),
                              fmaxf(sc[m][2][r], sc[m][3][r]));
            #pragma unroll
            for (int off = 1; off < 16; off <<= 1) {
                #pragma unroll
                for (int r = 0; r < 4; ++r)
                    mx[r] = fmaxf(mx[r], __shfl_xor(mx[r], off));
            }
            float al[4], rs[4];
            #pragma unroll
            for (int r = 0; r < 4; ++r) {
                float mn = fmaxf(m_i[m][r], mx[r]);
                al[r] = __builtin_amdgcn_exp2f(m_i[m][r] - mn);
                m_i[m][r] = mn;
                rs[r] = 0.f;
            }
            #pragma unroll
            for (int nb = 0; nb < 4; ++nb) {
                #pragma unroll
                for (int r = 0; r < 4; ++r) {
                    float p = __builtin_amdgcn_exp2f(sc[m][nb][r] - m_i[m][r]);
                    u16 hb = f2b(p);
                    Ps[w][m * 16 + quad * 4 + r][nb * 16 + ln] = hb;
                    rs[r] += b2f(hb);   // rounded value: num/denom consistent
                }
            }
            #pragma unroll
            for (int off = 1; off < 16; off <<= 1) {
                #pragma unroll
                for (int r = 0; r < 4; ++r) rs[r] += __shfl_xor(rs[r], off);
            }
            #pragma unroll
            for (int r = 0; r < 4; ++r) l_i[m][r] = l_i[m][r] * al[r] + rs[r];
            #pragma unroll
            for (int db = 0; db < 8; ++db) {
                #pragma unroll
                for (int r = 0; r < 4; ++r) o[m][db][r] *= al[r];
            }
        }

        // ---- O += P V, V frags shared across m-tiles ----
        short8 pf[2][2];
        #pragma unroll
        for (int m = 0; m < 2; ++m) {
            if (m == 0 && skip0) continue;
            #pragma unroll
            for (int kc = 0; kc < 2; ++kc)
                pf[m][kc] = *(const short8*)&Ps[w][m * 16 + ln][kc * 32 + quad * 8];
        }
        #pragma unroll
        for (int db = 0; db < 8; ++db) {
            short8 vf[2];
            #pragma unroll
            for (int kc = 0; kc < 2; ++kc) {
                int d = db * 16 + ln;
                vf[kc] = *(const short8*)&Vt[d * BN + (((kc * 4 + quad) ^ (d & 7)) << 3)];
            }
            if (!skip0) {
                o[0][db] = mfma16(pf[0][0], vf[0], o[0][db]);
                o[0][db] = mfma16(pf[0][1], vf[1], o[0][db]);
            }
            o[1][db] = mfma16(pf[1][0], vf[0], o[1][db]);
            o[1][db] = mfma16(pf[1][1], vf[1], o[1][db]);
        }
        __syncthreads();
    }

    // ---- epilogue: O / l ----
    #pragma unroll
    for (int m = 0; m < 2; ++m) {
        #pragma unroll
        for (int r = 0; r < 4; ++r) {
            float inv = 1.f / l_i[m][r];
            size_t row = (size_t)bh * S_LEN + rowb0 + m * 64 + quad * 4 + r;
            float* orow = out + row * D_DIM;
            #pragma unroll
            for (int db = 0; db < 8; ++db)
                orow[db * 16 + ln] = o[m][db][r] * inv;
        }
    }
}

// ---------------- fallback (round-1 kernel) if ws too small ----------------
#define KROW (D_DIM + 8)
#define VROW (64 + 8)
#define PROW (64 + 8)

__global__ __launch_bounds__(256) void fa_fwd(const float* __restrict__ q,
                                              const float* __restrict__ k,
                                              const float* __restrict__ v,
                                              float* __restrict__ out) {
    __shared__ u16 Ksf[64][KROW];
    __shared__ u16 Vtf[D_DIM][VROW];
    __shared__ u16 Psf[4][16][PROW];

    const int qt   = blockIdx.x;
    const int bh   = blockIdx.y;
    const int q0   = qt * 64;
    const int tid  = threadIdx.x;
    const int wave = tid >> 6;
    const int lane = tid & 63;
    const int ln   = lane & 15;
    const int quad = lane >> 4;
    const float scale = 0.08838834764831845f;

    const float* qrow = q + ((size_t)bh * S_LEN + q0 + wave * 16 + ln) * D_DIM;
    short8 qf[4];
    #pragma unroll
    for (int kc = 0; kc < 4; ++kc) {
        const float* p = qrow + kc * 32 + quad * 8;
        float4 x0 = *(const float4*)(p);
        float4 x1 = *(const float4*)(p + 4);
        short8 f;
        f[0] = (short)f2b(x0.x * scale); f[1] = (short)f2b(x0.y * scale);
        f[2] = (short)f2b(x0.z * scale); f[3] = (short)f2b(x0.w * scale);
        f[4] = (short)f2b(x1.x * scale); f[5] = (short)f2b(x1.y * scale);
        f[6] = (short)f2b(x1.z * scale); f[7] = (short)f2b(x1.w * scale);
        qf[kc] = f;
    }
    floatx4 o[8];
    #pragma unroll
    for (int db = 0; db < 8; ++db) o[db] = (floatx4){0.f, 0.f, 0.f, 0.f};
    float m_i[4] = {-1e30f, -1e30f, -1e30f, -1e30f};
    float l_i[4] = {0.f, 0.f, 0.f, 0.f};
    const size_t kvbase = (size_t)bh * S_LEN * D_DIM;

    for (int t = 0; t <= qt; ++t) {
        const int n0 = t * 64;
        const float* kb = k + kvbase + (size_t)n0 * D_DIM;
        const float* vb = v + kvbase + (size_t)n0 * D_DIM;
        #pragma unroll
        for (int i = 0; i < 8; ++i) {
            int e = i * 1024 + tid * 4;
            float4 x = *(const float4*)(kb + e);
            int r = e >> 7, c = e & 127;
            ushort4 h;
            h.x = f2b(x.x); h.y = f2b(x.y); h.z = f2b(x.z); h.w = f2b(x.w);
            *(ushort4*)&Ksf[r][c] = h;
        }
        #pragma unroll
        for (int u = 0; u < 2; ++u) {
            int unit = u * 256 + tid;
            int r = (unit >> 5) * 4;
            int c = (unit & 31) * 4;
            float4 x0 = *(const float4*)(vb + (r + 0) * D_DIM + c);
            float4 x1 = *(const float4*)(vb + (r + 1) * D_DIM + c);
            float4 x2 = *(const float4*)(vb + (r + 2) * D_DIM + c);
            float4 x3 = *(const float4*)(vb + (r + 3) * D_DIM + c);
            ushort4 h;
            h.x = f2b(x0.x); h.y = f2b(x1.x); h.z = f2b(x2.x); h.w = f2b(x3.x);
            *(ushort4*)&Vtf[c + 0][r] = h;
            h.x = f2b(x0.y); h.y = f2b(x1.y); h.z = f2b(x2.y); h.w = f2b(x3.y);
            *(ushort4*)&Vtf[c + 1][r] = h;
            h.x = f2b(x0.z); h.y = f2b(x1.z); h.z = f2b(x2.z); h.w = f2b(x3.z);
            *(ushort4*)&Vtf[c + 2][r] = h;
            h.x = f2b(x0.w); h.y = f2b(x1.w); h.z = f2b(x2.w); h.w = f2b(x3.w);
            *(ushort4*)&Vtf[c + 3][r] = h;
        }
        __syncthreads();
        floatx4 sc[4];
        #pragma unroll
        for (int nb = 0; nb < 4; ++nb) {
            floatx4 acc = (floatx4){0.f, 0.f, 0.f, 0.f};
            #pragma unroll
            for (int kc = 0; kc < 4; ++kc) {
                short8 bfr = *(const short8*)&Ksf[nb * 16 + ln][kc * 32 + quad * 8];
                acc = __builtin_amdgcn_mfma_f32_16x16x32_bf16(qf[kc], bfr, acc, 0, 0, 0);
            }
            sc[nb] = acc;
        }
        if (t == qt) {
            int rowg = q0 + wave * 16 + quad * 4;
            #pragma unroll
            for (int nb = 0; nb < 4; ++nb) {
                int colg = n0 + nb * 16 + ln;
                #pragma unroll
                for (int r = 0; r < 4; ++r)
                    if (colg > rowg + r) sc[nb][r] = -1e30f;
            }
        }
        float mx[4];
        #pragma unroll
        for (int r = 0; r < 4; ++r)
            mx[r] = fmaxf(fmaxf(sc[0][r], sc[1][r]), fmaxf(sc[2][r], sc[3][r]));
        #pragma unroll
        for (int off = 1; off < 16; off <<= 1) {
            #pragma unroll
            for (int r = 0; r < 4; ++r)
                mx[r] = fmaxf(mx[r], __shfl_xor(mx[r], off));
        }
        float al[4], rs[4];
        #pragma unroll
        for (int r = 0; r < 4; ++r) {
            float mn = fmaxf(m_i[r], mx[r]);
            al[r] = __expf(m_i[r] - mn);
            m_i[r] = mn;
            rs[r] = 0.f;
        }
        #pragma unroll
        for (int nb = 0; nb < 4; ++nb) {
            #pragma unroll
            for (int r = 0; r < 4; ++r) {
                float p = __expf(sc[nb][r] - m_i[r]);
                u16 hb = f2b(p);
                Psf[wave][quad * 4 + r][nb * 16 + ln] = hb;
                rs[r] += b2f(hb);
            }
        }
        #pragma unroll
        for (int off = 1; off < 16; off <<= 1) {
            #pragma unroll
            for (int r = 0; r < 4; ++r) rs[r] += __shfl_xor(rs[r], off);
        }
        #pragma unroll
        for (int r = 0; r < 4; ++r) l_i[r] = l_i[r] * al[r] + rs[r];
        #pragma unroll
        for (int db = 0; db < 8; ++db) {
            #pragma unroll
            for (int r = 0; r < 4; ++r) o[db][r] *= al[r];
        }
        short8 pf[2];
        #pragma unroll
        for (int kc = 0; kc < 2; ++kc)
            pf[kc] = *(const short8*)&Psf[wave][ln][kc * 32 + quad * 8];
        #pragma unroll
        for (int db = 0; db < 8; ++db) {
            floatx4 acc = o[db];
            #pragma unroll
            for (int kc = 0; kc < 2; ++kc) {
                short8 vf = *(const short8*)&Vtf[db * 16 + ln][kc * 32 + quad * 8];
                acc = __builtin_amdgcn_mfma_f32_16x16x32_bf16(pf[kc], vf, acc, 0, 0, 0);
            }
            o[db] = acc;
        }
        __syncthreads();
    }
    #pragma unroll
    for (int r = 0; r < 4; ++r) {
        float inv = 1.f / l_i[r];
        size_t row = (size_t)bh * S_LEN + q0 + wave * 16 + quad * 4 + r;
        #pragma unroll
        for (int db = 0; db < 8; ++db)
            out[row * D_DIM + db * 16 + ln] = o[db][r] * inv;
    }
}

extern "C" void kernel_launch(void* const* d_in, const int* in_sizes, int n_in,
                              void* d_out, int out_size, void* d_ws, size_t ws_size,
                              hipStream_t stream) {
    const float* q = (const float*)d_in[0];
    const float* k = (const float*)d_in[1];
    const float* v = (const float*)d_in[2];
    float* out = (float*)d_out;
    const int bh = in_sizes[0] / (S_LEN * D_DIM);          // 32
    const size_t kelems = (size_t)bh * S_LEN * D_DIM;      // 8.39M
    const size_t need = kelems * 2 * sizeof(u16);          // K + Vt bf16

    if (ws_size >= need) {
        u16* kw = (u16*)d_ws;
        u16* vt = kw + kelems;
        conv_k<<<(int)(kelems / 1024), 256, 0, stream>>>(k, kw);
        trans_v<<<dim3(S_LEN / 64, bh), 256, 0, stream>>>(v, vt);
        fa_main<<<dim3(S_LEN / BM, bh), 256, 0, stream>>>(q, kw, vt, out);
    } else {
        fa_fwd<<<dim3(S_LEN / 64, bh), 256, 0, stream>>>(q, k, v, out);
    }
}